// Round 1
// baseline (930.929 us; speedup 1.0000x reference)
//
#include <hip/hip_runtime.h>

// Problem: N=1024, D=32, IN_F=128, OUT_F=128
//   f      = tanh(u@K + b)                  (N,128)            -> out[0 ..)
//   dfdx   = dsig * (dudx@K)                (N,32,128)         -> out[131072 ..)
//   d2fd2x = d2sig*A_d*A_e + dsig*(d2ud2x@K) (N,32,32,128)     -> out[4325376 ..)
//
// R1 redesign: k_dfdx/k_hess have ZERO cross-lane reuse of X (each input row
// feeds exactly one output row), so LDS staging was pure overhead:
//   - deleted LDS + both per-chunk barriers (full vmcnt/lgkmcnt drains)
//   - K fragments hoisted into 128 VGPRs/lane (512 B), loaded once per wave
//   - per-lane MFMA A-fragments loaded DIRECTLY from global (two float4 per
//     k-step; lanes cover 128-B contiguous segments -> fully coalesced),
//     packed f32->bf16 in-register with the same RNE as before.
// Per-lane bytes fed to the MFMA are bit-identical to the old LDS path, so
// numerics (and the passing absmax=0.03125) are unchanged.
//
// Workspace layout (floats) — unchanged:
//   [0          .. 131072)   dsig
//   [131072     .. 262144)   d2sig
//   [262144     .. 270336)   Kt as bf16 (16384 ushorts = 32 KB)
//   [270336     .. 4464640)  A = dudx@K (f32)

typedef __bf16 bf16x8 __attribute__((ext_vector_type(8)));
typedef float f32x4 __attribute__((ext_vector_type(4)));

__device__ __forceinline__ unsigned int pk2bf(float a, float b) {
    unsigned int ua = __builtin_bit_cast(unsigned int, a);
    unsigned int ub = __builtin_bit_cast(unsigned int, b);
    ua = (ua + 0x7FFFu + ((ua >> 16) & 1u)) >> 16;   // RNE
    ub = (ub + 0x7FFFu + ((ub >> 16) & 1u)) >> 16;
    return ua | (ub << 16);
}

// ---------------- k_prep: f, dsig, d2sig (unchanged, tiny) ----------------
__global__ __launch_bounds__(256) void k_prep(const float* __restrict__ u,
                                              const float* __restrict__ K,
                                              const float* __restrict__ b,
                                              float* __restrict__ f_out,
                                              float* __restrict__ dsig,
                                              float* __restrict__ d2sig) {
    __shared__ float us[16][128];
    const int t = threadIdx.x;
    const int blk = blockIdx.x;   // 64 blocks x 16 rows
    {
        int row = t >> 4, c = (t & 15) * 8;
        const float4* src = reinterpret_cast<const float4*>(u + (blk * 16 + row) * 128 + c);
        float4 v0 = src[0], v1 = src[1];
        *reinterpret_cast<float4*>(&us[row][c])     = v0;
        *reinterpret_cast<float4*>(&us[row][c + 4]) = v1;
    }
    __syncthreads();
    const int o = t & 127;
    const int rr = (t >> 7) * 8;
    float acc[8] = {0.f, 0.f, 0.f, 0.f, 0.f, 0.f, 0.f, 0.f};
    for (int i = 0; i < 128; ++i) {
        float kv = K[i * 128 + o];
#pragma unroll
        for (int j = 0; j < 8; ++j) acc[j] = fmaf(us[rr + j][i], kv, acc[j]);
    }
    const float bv = b[o];
#pragma unroll
    for (int j = 0; j < 8; ++j) {
        int row = blk * 16 + rr + j;
        float z = acc[j] + bv;
        float fv = tanhf(z);
        float ds = 1.0f - fv * fv;
        f_out[row * 128 + o] = fv;
        dsig[row * 128 + o] = ds;
        d2sig[row * 128 + o] = -2.0f * fv * ds;
    }
}

// ---------------- k_kt: Kt[o][i] = bf16(K[i][o]) ----------------
__global__ __launch_bounds__(128) void k_kt(const float* __restrict__ K,
                                            unsigned short* __restrict__ kt) {
    const int o = blockIdx.x, i = threadIdx.x;
    unsigned int v = __builtin_bit_cast(unsigned int, K[i * 128 + o]);
    v = (v + 0x7FFFu + ((v >> 16) & 1u)) >> 16;
    kt[o * 128 + i] = (unsigned short)v;
}

// ---------------- register-resident K fragments ----------------
// B-frag for (c,s): Kt[n = c*16 + l][k = s*32 + q*8 .. +8]  (16 B, aligned).
// 8c x 4s x 4 VGPR = 128 VGPRs/lane. L2-resident broadcast across waves.
__device__ __forceinline__ void load_kfrag(const unsigned short* __restrict__ kt,
                                           int q, int l, bf16x8 (&kf)[8][4]) {
#pragma unroll
    for (int c = 0; c < 8; ++c)
#pragma unroll
        for (int s = 0; s < 4; ++s)
            kf[c][s] = *reinterpret_cast<const bf16x8*>(kt + (c * 16 + l) * 128 + s * 32 + q * 8);
}

// One 16-row x 128-col tile: direct-global A-fragments + 32 MFMAs.
// xrow = X + (m0 + l)*128 : lane (q,l) reads row m0+l, floats [s*32+q*8, +8).
// Per instruction the wave covers 16 rows x 128-B contiguous segments.
__device__ __forceinline__ void tile_gemm(const float* __restrict__ xrow, int q,
                                          const bf16x8 (&kf)[8][4], f32x4 (&acc)[8]) {
    float4 v0[4], v1[4];
#pragma unroll
    for (int s = 0; s < 4; ++s) {
        const float4* p = reinterpret_cast<const float4*>(xrow) + (s * 8 + q * 2);
        v0[s] = p[0];
        v1[s] = p[1];
    }
#pragma unroll
    for (int s = 0; s < 4; ++s) {
        uint4 wv;
        wv.x = pk2bf(v0[s].x, v0[s].y);
        wv.y = pk2bf(v0[s].z, v0[s].w);
        wv.z = pk2bf(v1[s].x, v1[s].y);
        wv.w = pk2bf(v1[s].z, v1[s].w);
        bf16x8 a = __builtin_bit_cast(bf16x8, wv);
#pragma unroll
        for (int c = 0; c < 8; ++c)
            acc[c] = __builtin_amdgcn_mfma_f32_16x16x32_bf16(a, kf[c][s], acc[c], 0, 0, 0);
    }
}

// ---------------- k_dfdx: A = dudx@K (->ws), dfdx = dsig*A (->out) ----------------
// 512 blocks x 4 waves = 2048 waves; one 16-row tile each (M = N*D = 32768).
__global__ __launch_bounds__(256, 2) void k_dfdx(const float* __restrict__ dudx,
                                                 const unsigned short* __restrict__ kt,
                                                 const float* __restrict__ dsig,
                                                 float* __restrict__ wsA,
                                                 float* __restrict__ dfdx_out) {
    const int t = threadIdx.x, w = t >> 6, lane = t & 63, q = lane >> 4, l = lane & 15;
    bf16x8 kf[8][4];
    load_kfrag(kt, q, l, kf);

    const int wid = blockIdx.x * 4 + w;
    const int m0 = wid * 16;
    f32x4 acc[8];
#pragma unroll
    for (int c = 0; c < 8; ++c) acc[c] = (f32x4){0.f, 0.f, 0.f, 0.f};
    tile_gemm(dudx + (size_t)(m0 + l) * 128, q, kf, acc);

    const int n = m0 >> 5;            // constant across the wave tile
    const float* dsp = dsig + n * 128;
    float* ap = wsA + (size_t)m0 * 128;
    float* dp = dfdx_out + (size_t)m0 * 128;
#pragma unroll
    for (int c = 0; c < 8; ++c) {
        int o = c * 16 + l;
        float ds = dsp[o];
#pragma unroll
        for (int r = 0; r < 4; ++r) {
            int ri = q * 4 + r;
            float a = acc[c][r];
            ap[ri * 128 + o] = a;
            dp[ri * 128 + o] = ds * a;
        }
    }
}

// ---------------- k_hess: d2fd2x = d2sig*Ad*Ae + dsig*(d2ud2x@K) ----------------
// 2048 blocks x 4 waves = 8192 waves; grid-stride over 65536 16-row tiles
// (M = N*D*D = 1048576). No LDS, no barriers; K stays in VGPRs across tiles.
__global__ __launch_bounds__(256, 2) void k_hess(const float* __restrict__ X,
                                                 const unsigned short* __restrict__ kt,
                                                 const float* __restrict__ dsig,
                                                 const float* __restrict__ d2sig,
                                                 const float* __restrict__ wsA,
                                                 float* __restrict__ out_h,
                                                 int ntiles) {
    const int t = threadIdx.x, w = t >> 6, lane = t & 63, q = lane >> 4, l = lane & 15;
    bf16x8 kf[8][4];
    load_kfrag(kt, q, l, kf);

    const int wid = blockIdx.x * 4 + w;
    const int nw = gridDim.x * 4;
    for (int tile = wid; tile < ntiles; tile += nw) {
        const int m0 = tile * 16;
        f32x4 acc[8];
#pragma unroll
        for (int c = 0; c < 8; ++c) acc[c] = (f32x4){0.f, 0.f, 0.f, 0.f};
        tile_gemm(X + (size_t)(m0 + l) * 128, q, kf, acc);

        // row m = m0 + q*4 + r;  n = m>>10, d = (m>>5)&31, e = (m&31)
        const int n = m0 >> 10;        // constant per tile
        const int d = (m0 >> 5) & 31;  // constant per tile
        const int e0 = m0 & 31;        // e = e0 + q*4 + r (tile stays in one d)
        const float* dsp = dsig + n * 128;
        const float* d2p = d2sig + n * 128;
        const float* Adp = wsA + (size_t)(n * 32 + d) * 128;
        const float* Aep = wsA + (size_t)(n * 32 + e0) * 128;
        float* outp = out_h + (size_t)m0 * 128;
#pragma unroll
        for (int c = 0; c < 8; ++c) {
            int o = c * 16 + l;
            float ds = dsp[o];
            float tt = d2p[o] * Adp[o];   // d2sig * A_d
#pragma unroll
            for (int r = 0; r < 4; ++r) {
                int ri = q * 4 + r;
                float Ae = Aep[(size_t)ri * 128 + o];
                outp[(size_t)ri * 128 + o] = fmaf(ds, acc[c][r], tt * Ae);
            }
        }
    }
}

extern "C" void kernel_launch(void* const* d_in, const int* in_sizes, int n_in,
                              void* d_out, int out_size, void* d_ws, size_t ws_size,
                              hipStream_t stream) {
    const float* u      = (const float*)d_in[0];
    const float* dudx   = (const float*)d_in[1];
    const float* d2ud2x = (const float*)d_in[2];
    const float* K      = (const float*)d_in[3];
    const float* b      = (const float*)d_in[4];

    float* out = (float*)d_out;
    float* f_out    = out;                       // 1024*128
    float* dfdx_out = out + 131072;              // 1024*32*128
    float* hess_out = out + 131072 + 4194304;    // 1024*32*32*128

    float* ws = (float*)d_ws;
    float* dsig  = ws;                           // 131072
    float* d2sig = ws + 131072;                  // 131072
    unsigned short* kt = (unsigned short*)(ws + 262144);  // 16384 bf16
    float* wsA   = ws + 262144 + 8192;           // 4194304 (A, f32)

    k_prep<<<64, 256, 0, stream>>>(u, K, b, f_out, dsig, d2sig);
    k_kt<<<128, 128, 0, stream>>>(K, kt);
    k_dfdx<<<512, 256, 0, stream>>>(dudx, kt, dsig, wsA, dfdx_out);
    k_hess<<<2048, 256, 0, stream>>>(d2ud2x, kt, dsig, d2sig, wsA, hess_out, 65536);
}